// Round 7
// baseline (53.407 us; speedup 1.0000x reference)
//
#include <hip/hip_runtime.h>

#define LN_EPS 1e-5f
#define D 256
#define V 256

typedef float fv4 __attribute__((ext_vector_type(4)));

// Kernel 1: build per-token-id logits table T[V][V]. (unchanged from R3/R4 —
// kept identical for cross-round attribution; launched 4x this round as a
// duration probe: total - 25.6 ~= 3 * build_duration)
__global__ __launch_bounds__(256) void build_table(
    const float* __restrict__ embed,   // [V, D]
    const float* __restrict__ filt,    // [D]
    const float* __restrict__ lnw,     // [D]
    const float* __restrict__ lnb,     // [D]
    const float* __restrict__ Wout,    // [V, D]
    const float* __restrict__ bout,    // [V]
    float* __restrict__ T)             // [V, V]
{
    const int v  = blockIdx.x >> 2;
    const int u0 = (blockIdx.x & 3) << 6;   // 64-wide u slab
    const int t  = threadIdx.x;

    __shared__ fv4 hn4[D / 4];
    __shared__ float red[8];

    // FFT mixing + residual == scale channel d by (1 + filter[d])
    float e = embed[v * D + t] * (1.0f + filt[t]);

    // block reduction for mean / var (4 waves of 64)
    float s = e, sq = e * e;
    #pragma unroll
    for (int off = 32; off > 0; off >>= 1) {
        s  += __shfl_down(s, off, 64);
        sq += __shfl_down(sq, off, 64);
    }
    const int wave = t >> 6;
    const int lane = t & 63;
    if (lane == 0) { red[wave * 2] = s; red[wave * 2 + 1] = sq; }
    __syncthreads();
    const float ts = red[0] + red[2] + red[4] + red[6];
    const float tq = red[1] + red[3] + red[5] + red[7];
    const float mu  = ts * (1.0f / D);
    const float var = tq * (1.0f / D) - mu * mu;
    const float inv = rsqrtf(var + LN_EPS);

    ((float*)hn4)[t] = (e - mu) * inv * lnw[t] + lnb[t];
    __syncthreads();

    // Phase 2: wave handles u = u0 + wave*16 + k, k = 0..15.
    const fv4 h = hn4[lane];            // this lane's d-slice, reused 16×
    const fv4* __restrict__ W4 = (const fv4*)Wout;

    #pragma unroll 4
    for (int k = 0; k < 16; ++k) {
        const int u = u0 + wave * 16 + k;
        const fv4 w = W4[u * (D / 4) + lane];   // coalesced: 64 lanes × 16B
        fv4 p = h * w;
        float d = (p.x + p.y) + (p.z + p.w);
        #pragma unroll
        for (int m = 32; m > 0; m >>= 1)
            d += __shfl_xor(d, m, 64);
        if (lane == 0)
            T[v * V + u] = bout[u] + d;
    }
}

// Kernel 2 (production, measured ~11.4us standalone = ~0.9x of write floor):
// out[token, :] = T[x[token], :], one float4 per thread, flat grid, NT store.
__global__ __launch_bounds__(256) void gather_flat(
    const int* __restrict__ x,        // [B*L] token ids
    const fv4* __restrict__ T4,       // [V * (V/4)]
    fv4* __restrict__ out4)           // [B*L * (V/4)]
{
    const int i = blockIdx.x * 256 + threadIdx.x;
    const int tok = x[i >> 6];                 // V/4 = 64 float4 per row
    const fv4 val = T4[(tok << 6) | (i & 63)];
    __builtin_nontemporal_store(val, &out4[i]);
}

extern "C" void kernel_launch(void* const* d_in, const int* in_sizes, int n_in,
                              void* d_out, int out_size, void* d_ws, size_t ws_size,
                              hipStream_t stream) {
    const int*   x     = (const int*)  d_in[0];   // [B*L] = 65536
    const float* embed = (const float*)d_in[1];   // [256,256]
    const float* filt  = (const float*)d_in[2];   // [256]
    const float* lnw   = (const float*)d_in[3];
    const float* lnb   = (const float*)d_in[4];
    const float* Wout  = (const float*)d_in[5];   // [256,256]
    const float* bout  = (const float*)d_in[6];   // [256]
    float* out = (float*)d_out;

    float* T = (float*)d_ws;                      // 256*256*4 = 256 KB scratch

    // Probe: 4 identical (idempotent) builds. total - 25.6 ~= 3 * build.
    build_table<<<V * 4, 256, 0, stream>>>(embed, filt, lnw, lnb, Wout, bout, T);
    build_table<<<V * 4, 256, 0, stream>>>(embed, filt, lnw, lnb, Wout, bout, T);
    build_table<<<V * 4, 256, 0, stream>>>(embed, filt, lnw, lnb, Wout, bout, T);
    build_table<<<V * 4, 256, 0, stream>>>(embed, filt, lnw, lnb, Wout, bout, T);

    const int n_tok  = in_sizes[0];               // 65536
    const int total4 = n_tok * (V / 4);           // 4,194,304 float4
    gather_flat<<<total4 / 256, 256, 0, stream>>>(x, (const fv4*)T, (fv4*)out);
}

// Round 8
// 21.159 us; speedup vs baseline: 2.5241x; 2.5241x over previous
//
#include <hip/hip_runtime.h>

#define LN_EPS 1e-5f
#define D 256
#define V 256

typedef float fv4 __attribute__((ext_vector_type(4)));

// Kernel 1: build per-token-id logits table T[V][V].
// Grid = V*8: block (v = bid>>3, ug = bid&7) computes T[v, ug*32 .. ug*32+31].
// 8 blocks/CU -> full occupancy. 16-lane group g computes logit u; lane l
// handles d-slices {c*64 + l*4 .. +3, c=0..3}: all global/LDS reads
// conflict-free & coalesced, reduction is a 4-step shfl_xor tree.
__global__ __launch_bounds__(256) void build_table(
    const float* __restrict__ embed,   // [V, D]
    const float* __restrict__ filt,    // [D]
    const float* __restrict__ lnw,     // [D]
    const float* __restrict__ lnb,     // [D]
    const float* __restrict__ Wout,    // [V, D]
    const float* __restrict__ bout,    // [V]
    float* __restrict__ T)             // [V, V]
{
    const int v  = blockIdx.x >> 3;
    const int u0 = (blockIdx.x & 7) << 5;   // 32-wide u slab
    const int t  = threadIdx.x;

    __shared__ float hn[D];
    __shared__ float red[8];

    // FFT mixing + residual == scale channel d by (1 + filter[d])
    float e = embed[v * D + t] * (1.0f + filt[t]);

    // block reduction for mean / var (4 waves of 64)
    float s = e, sq = e * e;
    #pragma unroll
    for (int off = 32; off > 0; off >>= 1) {
        s  += __shfl_down(s, off, 64);
        sq += __shfl_down(sq, off, 64);
    }
    const int wave = t >> 6;
    const int lane = t & 63;
    if (lane == 0) { red[wave * 2] = s; red[wave * 2 + 1] = sq; }
    __syncthreads();
    const float ts = red[0] + red[2] + red[4] + red[6];
    const float tq = red[1] + red[3] + red[5] + red[7];
    const float mu  = ts * (1.0f / D);
    const float var = tq * (1.0f / D) - mu * mu;
    const float inv = rsqrtf(var + LN_EPS);

    hn[t] = (e - mu) * inv * lnw[t] + lnb[t];
    __syncthreads();

    const int g = t >> 4;     // group 0..15 -> logit index within slab
    const int l = t & 15;     // lane within group -> d-slice

    // Per-thread h slices (LDS, conflict-free: lanes 0-15 read 256B contig).
    const fv4* __restrict__ hn4 = (const fv4*)hn;
    fv4 hb0 = hn4[0 * 16 + l];
    fv4 hb1 = hn4[1 * 16 + l];
    fv4 hb2 = hn4[2 * 16 + l];
    fv4 hb3 = hn4[3 * 16 + l];

    const fv4* __restrict__ W4 = (const fv4*)Wout;

    #pragma unroll
    for (int j = 0; j < 2; ++j) {
        const int u = u0 + j * 16 + g;
        const fv4* __restrict__ Wrow = W4 + u * (D / 4);
        // load c: group's 16 lanes read 256B contiguous (coalesced)
        fv4 acc = hb0 * Wrow[0 * 16 + l];
        acc += hb1 * Wrow[1 * 16 + l];
        acc += hb2 * Wrow[2 * 16 + l];
        acc += hb3 * Wrow[3 * 16 + l];
        float d = (acc.x + acc.y) + (acc.z + acc.w);
        d += __shfl_xor(d, 1, 16);
        d += __shfl_xor(d, 2, 16);
        d += __shfl_xor(d, 4, 16);
        d += __shfl_xor(d, 8, 16);
        if (l == 0)
            T[v * V + u] = bout[u] + d;
    }
}

// Kernel 2 (measured ~11.4us standalone ~= 0.9x write floor):
// out[token, :] = T[x[token], :], one float4 per thread, flat grid, NT store.
__global__ __launch_bounds__(256) void gather_flat(
    const int* __restrict__ x,        // [B*L] token ids
    const fv4* __restrict__ T4,       // [V * (V/4)]
    fv4* __restrict__ out4)           // [B*L * (V/4)]
{
    const int i = blockIdx.x * 256 + threadIdx.x;
    const int tok = x[i >> 6];                 // V/4 = 64 float4 per row
    const fv4 val = T4[(tok << 6) | (i & 63)];
    __builtin_nontemporal_store(val, &out4[i]);
}

extern "C" void kernel_launch(void* const* d_in, const int* in_sizes, int n_in,
                              void* d_out, int out_size, void* d_ws, size_t ws_size,
                              hipStream_t stream) {
    const int*   x     = (const int*)  d_in[0];   // [B*L] = 65536
    const float* embed = (const float*)d_in[1];   // [256,256]
    const float* filt  = (const float*)d_in[2];   // [256]
    const float* lnw   = (const float*)d_in[3];
    const float* lnb   = (const float*)d_in[4];
    const float* Wout  = (const float*)d_in[5];   // [256,256]
    const float* bout  = (const float*)d_in[6];   // [256]
    float* out = (float*)d_out;

    float* T = (float*)d_ws;                      // 256*256*4 = 256 KB scratch

    build_table<<<V * 8, 256, 0, stream>>>(embed, filt, lnw, lnb, Wout, bout, T);

    const int n_tok  = in_sizes[0];               // 65536
    const int total4 = n_tok * (V / 4);           // 4,194,304 float4
    gather_flat<<<total4 / 256, 256, 0, stream>>>(x, (const fv4*)T, (fv4*)out);
}